// Round 9
// baseline (4354.221 us; speedup 1.0000x reference)
//
#include <hip/hip_runtime.h>

// Model: B=32, L1=512, L2=16, D=300, H=300, V=50000, C=3
#define B_  32
#define L1_ 512
#define L2_ 16
#define D_  300
#define H_  300

__device__ __forceinline__ float sigmoid_fast(float x) {
    return 1.0f / (1.0f + __expf(-x));
}
__device__ __forceinline__ float tanh_fast(float x) {
    x = fminf(fmaxf(x, -15.0f), 15.0f);
    float e = __expf(2.0f * x);
    return (e - 1.0f) / (e + 1.0f);
}
// accurate versions for the GRU recurrence (R4/R5/R7 evidence: large margin)
__device__ __forceinline__ float sigmoid_acc(float x) {
    return 1.0f / (1.0f + expf(-x));
}
__device__ __forceinline__ float wred_sum(float v) {
    #pragma unroll
    for (int off = 32; off > 0; off >>= 1) v += __shfl_xor(v, off);
    return v;
}
__device__ __forceinline__ float wred_max(float v) {
    #pragma unroll
    for (int off = 32; off > 0; off >>= 1) v = fmaxf(v, __shfl_xor(v, off));
    return v;
}

// device-coherent (LLC) 8-byte packet ops: sc0 sc1 = bypass L1+L2, no invalidates
__device__ __forceinline__ void store_pkt(long long* p, long long v) {
    asm volatile("global_store_dwordx2 %0, %1, off sc0 sc1" :: "v"(p), "v"(v) : "memory");
}
// two tagged loads in flight, one wait
__device__ __forceinline__ void load_pkt2(const long long* p1, const long long* p2,
                                          long long& v1, long long& v2) {
    asm volatile("global_load_dwordx2 %0, %2, off sc0 sc1\n\t"
                 "global_load_dwordx2 %1, %3, off sc0 sc1\n\t"
                 "s_waitcnt vmcnt(0)"
                 : "=&v"(v1), "=&v"(v2) : "v"(p1), "v"(p2) : "memory");
}

// Workgroup barrier that drains ONLY lgkmcnt (LDS), not vmcnt: keeps the
// publish-store ACK off the critical path (tag protocol owns global visibility).
// sched_barrier + memory clobber fence compiler motion (rule #18).
__device__ __forceinline__ void wg_barrier() {
    __builtin_amdgcn_sched_barrier(0);
    asm volatile("s_waitcnt lgkmcnt(0)" ::: "memory");
    __builtin_amdgcn_s_barrier();
    __builtin_amdgcn_sched_barrier(0);
}

// ---------------- gather rows of emb (row length 300 = 75 float4) ----------------
__global__ __launch_bounds__(256) void gather_kernel(const float* __restrict__ emb,
                                                     const int* __restrict__ ids,
                                                     float* __restrict__ out, int total) {
    for (int i = blockIdx.x * 256 + threadIdx.x; i < total; i += gridDim.x * 256) {
        int row = i / 75, c = i % 75;
        int id = ids[row];
        reinterpret_cast<float4*>(out)[i] =
            reinterpret_cast<const float4*>(emb + (size_t)id * 300)[c];
    }
}

// ---------------- fp32 GEMM: C[M,N] = A[M,K] @ W[N,K]^T (+ bias[n]) ----------------
#define TM 128
#define TN 64
#define TK 16
__device__ __forceinline__ int bcol(int c) { return c + ((c >> 5) << 2); }
__global__ __launch_bounds__(256) void gemm_nt(const float* __restrict__ A,
                                               const float* __restrict__ W,
                                               const float* __restrict__ bias,
                                               float* __restrict__ C,
                                               int M, int N, int K) {
    __shared__ __align__(16) float As[TK][TM + 4];
    __shared__ __align__(16) float Bs[TK][76];
    const int tid = threadIdx.x;
    const int m0 = blockIdx.x * TM;
    const int n0 = blockIdx.y * TN;
    const int tx = tid & 15;
    const int ty = tid >> 4;
    const int lr = tid >> 2;
    const int lk = (tid & 3) << 2;

    float acc[8][4];
    #pragma unroll
    for (int i = 0; i < 8; ++i)
        #pragma unroll
        for (int j = 0; j < 4; ++j) acc[i][j] = 0.f;

    for (int k0 = 0; k0 < K; k0 += TK) {
        const bool kok = (k0 + lk + 3) < K;
        #pragma unroll
        for (int h = 0; h < 2; ++h) {
            float4 v = make_float4(0.f, 0.f, 0.f, 0.f);
            int m = m0 + lr + 64 * h;
            if (kok) v = *reinterpret_cast<const float4*>(&A[(size_t)m * K + k0 + lk]);
            As[lk + 0][lr + 64 * h] = v.x;
            As[lk + 1][lr + 64 * h] = v.y;
            As[lk + 2][lr + 64 * h] = v.z;
            As[lk + 3][lr + 64 * h] = v.w;
        }
        {
            float4 v = make_float4(0.f, 0.f, 0.f, 0.f);
            int n = n0 + lr;
            if (kok && n < N) v = *reinterpret_cast<const float4*>(&W[(size_t)n * K + k0 + lk]);
            const int lrp = bcol(lr);
            Bs[lk + 0][lrp] = v.x;
            Bs[lk + 1][lrp] = v.y;
            Bs[lk + 2][lrp] = v.z;
            Bs[lk + 3][lrp] = v.w;
        }
        __syncthreads();
        #pragma unroll
        for (int k = 0; k < TK; ++k) {
            float4 a0 = *reinterpret_cast<const float4*>(&As[k][ty * 8]);
            float4 a1 = *reinterpret_cast<const float4*>(&As[k][ty * 8 + 4]);
            float4 bv = *reinterpret_cast<const float4*>(&Bs[k][bcol(tx * 4)]);
            float av[8] = {a0.x, a0.y, a0.z, a0.w, a1.x, a1.y, a1.z, a1.w};
            float bb[4] = {bv.x, bv.y, bv.z, bv.w};
            #pragma unroll
            for (int i = 0; i < 8; ++i)
                #pragma unroll
                for (int j = 0; j < 4; ++j) acc[i][j] += av[i] * bb[j];
        }
        __syncthreads();
    }
    #pragma unroll
    for (int i = 0; i < 8; ++i) {
        int m = m0 + ty * 8 + i;
        #pragma unroll
        for (int j = 0; j < 4; ++j) {
            int n = n0 + tx * 4 + j;
            if (n < N) C[(size_t)m * N + n] = acc[i][j] + (bias ? bias[n] : 0.f);
        }
    }
}

// ---------------- attention: scores -> alpha -> context_ -> beta logits ----------------
__global__ __launch_bounds__(256) void attn_kernel(const float* __restrict__ c_proj,
                                                   const float* __restrict__ a_proj,
                                                   const float* __restrict__ asp_emb,
                                                   const float* __restrict__ lin,
                                                   const float* __restrict__ Vatt,
                                                   const float* __restrict__ Vw,
                                                   const float* __restrict__ bVw,
                                                   float* __restrict__ blogit) {
    const int b = blockIdx.y;
    const int chunk = blockIdx.x;
    __shared__ float sA[16 * 300];
    __shared__ float sE[16 * 300];
    __shared__ float sV[300];
    __shared__ float sW[300];
    const int tid = threadIdx.x;
    for (int i = tid; i < 16 * 300; i += 256) {
        sA[i] = a_proj[b * 4800 + i];
        sE[i] = asp_emb[b * 4800 + i];
    }
    for (int i = tid; i < 300; i += 256) {
        sV[i] = Vatt[i];
        sW[i] = Vw[i];
    }
    __syncthreads();
    const int wave = tid >> 6, lane = tid & 63;
    const float bvw = bVw[0];
    for (int li = 0; li < 4; ++li) {
        const int l = chunk * 16 + wave * 4 + li;
        const float* crow = c_proj + (size_t)(b * L1_ + l) * 300;
        float cr[5];
        #pragma unroll
        for (int i = 0; i < 5; ++i) {
            int d = lane + 64 * i;
            cr[i] = (d < 300) ? crow[d] : 0.f;
        }
        float sc[16];
        #pragma unroll
        for (int m = 0; m < 16; ++m) {
            float s = 0.f;
            #pragma unroll
            for (int i = 0; i < 5; ++i) {
                int d = lane + 64 * i;
                if (d < 300) s += tanh_fast(cr[i] + sA[m * 300 + d]) * sV[d];
            }
            s = wred_sum(s);
            sc[m] = s;
        }
        float mx = sc[0];
        #pragma unroll
        for (int m = 1; m < 16; ++m) mx = fmaxf(mx, sc[m]);
        float den = 0.f;
        #pragma unroll
        for (int m = 0; m < 16; ++m) {
            sc[m] = __expf(sc[m] - mx);
            den += sc[m];
        }
        const float inv = 1.f / den;
        const float* lrow = lin + (size_t)(b * L1_ + l) * 300;
        float acc = 0.f;
        #pragma unroll
        for (int i = 0; i < 5; ++i) {
            int d = lane + 64 * i;
            if (d < 300) {
                float cd = 0.f;
                #pragma unroll
                for (int m = 0; m < 16; ++m) cd += sc[m] * sE[m * 300 + d];
                acc += tanh_fast(lrow[d] + cd * inv) * sW[d];
            }
        }
        acc = wred_sum(acc);
        if (lane == 0) blogit[b * L1_ + l] = acc + bvw;
    }
}

// ---------------- beta softmax over L1=512 per batch ----------------
__global__ __launch_bounds__(256) void beta_softmax_kernel(const float* __restrict__ x,
                                                           float* __restrict__ y) {
    const int b = blockIdx.x, tid = threadIdx.x;
    __shared__ float red[4];
    const int wave = tid >> 6, lane = tid & 63;
    float v0 = x[b * 512 + tid];
    float v1 = x[b * 512 + 256 + tid];
    float m = wred_max(fmaxf(v0, v1));
    if (lane == 0) red[wave] = m;
    __syncthreads();
    m = fmaxf(fmaxf(red[0], red[1]), fmaxf(red[2], red[3]));
    float e0 = __expf(v0 - m), e1 = __expf(v1 - m);
    float s = wred_sum(e0 + e1);
    __syncthreads();
    if (lane == 0) red[wave] = s;
    __syncthreads();
    s = red[0] + red[1] + red[2] + red[3];
    const float inv = 1.f / s;
    y[b * 512 + tid] = e0 * inv;
    y[b * 512 + 256 + tid] = e1 * inv;
}

// ---------------- matvec over 300 cols from pinned registers ----------------
__device__ __forceinline__ float matvec300(const float4* h4, const float4 (&w4)[75],
                                           float bh) {
    float a0 = 0.f, a1 = 0.f, a2 = 0.f, a3 = 0.f;
    #pragma unroll
    for (int j = 0; j < 72; j += 4) {
        float4 hv;
        hv = h4[j];
        a0 = fmaf(w4[j].x, hv.x, a0); a0 = fmaf(w4[j].y, hv.y, a0);
        a0 = fmaf(w4[j].z, hv.z, a0); a0 = fmaf(w4[j].w, hv.w, a0);
        hv = h4[j + 1];
        a1 = fmaf(w4[j + 1].x, hv.x, a1); a1 = fmaf(w4[j + 1].y, hv.y, a1);
        a1 = fmaf(w4[j + 1].z, hv.z, a1); a1 = fmaf(w4[j + 1].w, hv.w, a1);
        hv = h4[j + 2];
        a2 = fmaf(w4[j + 2].x, hv.x, a2); a2 = fmaf(w4[j + 2].y, hv.y, a2);
        a2 = fmaf(w4[j + 2].z, hv.z, a2); a2 = fmaf(w4[j + 2].w, hv.w, a2);
        hv = h4[j + 3];
        a3 = fmaf(w4[j + 3].x, hv.x, a3); a3 = fmaf(w4[j + 3].y, hv.y, a3);
        a3 = fmaf(w4[j + 3].z, hv.z, a3); a3 = fmaf(w4[j + 3].w, hv.w, a3);
    }
    {
        float4 hv;
        hv = h4[72];
        a0 = fmaf(w4[72].x, hv.x, a0); a0 = fmaf(w4[72].y, hv.y, a0);
        a0 = fmaf(w4[72].z, hv.z, a0); a0 = fmaf(w4[72].w, hv.w, a0);
        hv = h4[73];
        a1 = fmaf(w4[73].x, hv.x, a1); a1 = fmaf(w4[73].y, hv.y, a1);
        a1 = fmaf(w4[73].z, hv.z, a1); a1 = fmaf(w4[73].w, hv.w, a1);
        hv = h4[74];
        a2 = fmaf(w4[74].x, hv.x, a2); a2 = fmaf(w4[74].y, hv.y, a2);
        a2 = fmaf(w4[74].z, hv.z, a2); a2 = fmaf(w4[74].w, hv.w, a2);
    }
    return bh + ((a0 + a1) + (a2 + a3));
}

// ---------------- GRU v9: fwd/bwd ping-pong, exchange latency hidden ----------------
// grid (8,32): WG k owns h elements [38k, 38k+38) of BOTH directions of batch b.
// 228 threads hold one whh row each (fwd rows 0-113, bwd rows 114-227), 300
// pinned floats/thread (gru7-proven). Per superstep s (fwd step s, bwd step
// 511-s), 4 phases:
//   P1: F-matvec (tid<114)        || poll bwd tag s-1 (tid>=114)
//   P2: F-gates + publish (tid<38)
//   P3: B-matvec (114<=tid<228)   || poll fwd tag s   (tid<114 | tid>=228)
//   P4: B-gates + publish (tid<38)
// Each direction's LLC publish->detect round trip overlaps the other
// direction's compute. Barriers drain lgkmcnt only (publish ACK off the path).
__global__ __launch_bounds__(256, 1) void gru9_kernel(const float* __restrict__ xg_f,
                                                      const float* __restrict__ xg_b,
                                                      const float* __restrict__ whh_f,
                                                      const float* __restrict__ whh_b,
                                                      const float* __restrict__ bhh_f,
                                                      const float* __restrict__ bhh_b,
                                                      const float* __restrict__ beta,
                                                      long long* __restrict__ slot, // [2][32][2][304]
                                                      float* __restrict__ senti) {
    const int k = blockIdx.x;    // slice 0..7
    const int b = blockIdx.y;    // 0..31
    const int tid = threadIdx.x;
    const int e0 = k * 38;
    const int own = (300 - e0 < 38) ? (300 - e0) : 38;   // 38 (k<7) or 34 (k=7)
    const int fcnt = 300 - own;                           // 262 or 266

    // row roles
    const bool isF = (tid < 114);
    const bool isB = (tid >= 114) && (tid < 228);
    int rgate = 0, ri = 0;
    if (isF) { rgate = tid / 38; ri = tid % 38; }
    else if (isB) { rgate = (tid - 114) / 38; ri = (tid - 114) % 38; }
    const int re = e0 + ri;
    const bool rowact = (isF || isB) && (re < 300);
    const float* whhp = isB ? whh_b : whh_f;
    const float* bhhp = isB ? bhh_b : bhh_f;

    // ---- weight row -> registers, asm-pinned (gru7-proven residency) ----
    float4 w4[75];
    float bh = 0.f;
    if (rowact) {
        const int row = rgate * 300 + re;
        bh = bhhp[row];
        const float4* wp = reinterpret_cast<const float4*>(whhp + (size_t)row * 300);
        #pragma unroll
        for (int j = 0; j < 75; ++j) w4[j] = wp[j];
    } else {
        #pragma unroll
        for (int j = 0; j < 75; ++j) w4[j] = make_float4(0.f, 0.f, 0.f, 0.f);
    }
    #pragma unroll
    for (int j = 0; j < 75; ++j)
        asm volatile("" : "+v"(w4[j].x), "+v"(w4[j].y), "+v"(w4[j].z), "+v"(w4[j].w));
    asm volatile("" : "+v"(bh));

    __shared__ __align__(16) float hs_f[304];
    __shared__ __align__(16) float hs_b[304];
    __shared__ float gg_f[3][40];
    __shared__ float gg_b[3][40];
    for (int i = tid; i < 304; i += 256) { hs_f[i] = 0.f; hs_b[i] = 0.f; }

    const int ge = e0 + tid;                       // gate-thread element (tid<38)
    const bool gact = (tid < 38) && (ge < 300);

    float sacc_f = 0.f, sacc_b = 0.f;
    int gaveup = 0;
    __syncthreads();

    const float4* hf4 = reinterpret_cast<const float4*>(hs_f);
    const float4* hb4 = reinterpret_cast<const float4*>(hs_b);

    for (int s = 0; s < 512; ++s) {
        // xg/beta prefetch for both directions (latency hides under P1)
        float xrf = 0.f, xzf = 0.f, xnf = 0.f, btf = 0.f;
        float xrb = 0.f, xzb = 0.f, xnb = 0.f, btb = 0.f;
        if (gact) {
            const float* xf = xg_f + (size_t)(b * 512 + s) * 900;
            xrf = xf[ge]; xzf = xf[300 + ge]; xnf = xf[600 + ge];
            btf = beta[b * 512 + s];
            const float* xb = xg_b + (size_t)(b * 512 + (511 - s)) * 900;
            xrb = xb[ge]; xzb = xb[300 + ge]; xnb = xb[600 + ge];
            btb = beta[b * 512 + (511 - s)];
        }
        // ---- P1: F-matvec || poll bwd(tag s-1) ----
        if (isF) {
            if (rowact) gg_f[rgate][ri] = matvec300(hf4, w4, bh);
        } else if (s > 0) {
            const int tag = s - 1;
            const size_t base = ((size_t)((tag & 1) * 64 + b * 2 + 1)) * 304;
            const int pid = tid - 114;                       // [0,142)
            int f1 = pid;        if (f1 >= fcnt) f1 = fcnt - 1;
            int f2 = pid + 142;  if (f2 >= fcnt) f2 = fcnt - 1;
            const int ee1 = (f1 < e0) ? f1 : f1 + own;
            const int ee2 = (f2 < e0) ? f2 : f2 + own;
            const long long* p1 = slot + base + ee1;
            const long long* p2 = slot + base + ee2;
            long long v1, v2;
            load_pkt2(p1, p2, v1, v2);
            if (!gaveup) {
                int it = 0;
                while (((int)(v1 >> 32)) != tag || ((int)(v2 >> 32)) != tag) {
                    if (++it >= (1 << 14)) { gaveup = 1; break; }
                    load_pkt2(p1, p2, v1, v2);
                }
            }
            hs_b[ee1] = __int_as_float((int)(v1 & 0xffffffffLL));
            hs_b[ee2] = __int_as_float((int)(v2 & 0xffffffffLL));
        }
        wg_barrier();
        // ---- P2: F-gates + publish ----
        if (gact) {
            const float rr = sigmoid_acc(xrf + gg_f[0][tid]);
            const float zz = sigmoid_acc(xzf + gg_f[1][tid]);
            const float nn = tanhf(xnf + rr * gg_f[2][tid]);
            const float hn = (1.f - zz) * nn + zz * hs_f[ge];
            sacc_f = fmaf(btf, hn, sacc_f);
            hs_f[ge] = hn;
            if (s < 511) {
                long long pkt = ((long long)(unsigned)s << 32) |
                                (unsigned)__float_as_int(hn);
                store_pkt(slot + ((size_t)((s & 1) * 64 + b * 2 + 0)) * 304 + ge, pkt);
            }
        }
        wg_barrier();
        // ---- P3: B-matvec || poll fwd(tag s) ----
        if (isB) {
            if (rowact) gg_b[rgate][ri] = matvec300(hb4, w4, bh);
        } else if (s < 511) {
            const int tag = s;
            const size_t base = ((size_t)((tag & 1) * 64 + b * 2 + 0)) * 304;
            const int pid = (tid < 114) ? tid : 114 + (tid - 228);  // [0,142)
            int f1 = pid;        if (f1 >= fcnt) f1 = fcnt - 1;
            int f2 = pid + 142;  if (f2 >= fcnt) f2 = fcnt - 1;
            const int ee1 = (f1 < e0) ? f1 : f1 + own;
            const int ee2 = (f2 < e0) ? f2 : f2 + own;
            const long long* p1 = slot + base + ee1;
            const long long* p2 = slot + base + ee2;
            long long v1, v2;
            load_pkt2(p1, p2, v1, v2);
            if (!gaveup) {
                int it = 0;
                while (((int)(v1 >> 32)) != tag || ((int)(v2 >> 32)) != tag) {
                    if (++it >= (1 << 14)) { gaveup = 1; break; }
                    load_pkt2(p1, p2, v1, v2);
                }
            }
            hs_f[ee1] = __int_as_float((int)(v1 & 0xffffffffLL));
            hs_f[ee2] = __int_as_float((int)(v2 & 0xffffffffLL));
        }
        wg_barrier();
        // ---- P4: B-gates + publish ----
        if (gact) {
            const float rr = sigmoid_acc(xrb + gg_b[0][tid]);
            const float zz = sigmoid_acc(xzb + gg_b[1][tid]);
            const float nn = tanhf(xnb + rr * gg_b[2][tid]);
            const float hn = (1.f - zz) * nn + zz * hs_b[ge];
            sacc_b = fmaf(btb, hn, sacc_b);
            hs_b[ge] = hn;
            if (s < 511) {
                long long pkt = ((long long)(unsigned)s << 32) |
                                (unsigned)__float_as_int(hn);
                store_pkt(slot + ((size_t)((s & 1) * 64 + b * 2 + 1)) * 304 + ge, pkt);
            }
        }
        wg_barrier();
    }
    if (gact) {
        senti[b * 600 + ge] = sacc_f;          // fwd half
        senti[b * 600 + 300 + ge] = sacc_b;    // bwd half
    }
}

// ---------------- final logits: (32,600) x (3,600)^T + outb ----------------
__global__ __launch_bounds__(64) void logits_kernel(const float* __restrict__ senti,
                                                    const float* __restrict__ outW,
                                                    const float* __restrict__ outb,
                                                    float* __restrict__ out) {
    const int b = blockIdx.x, lane = threadIdx.x;
    for (int c = 0; c < 3; ++c) {
        float s = 0.f;
        for (int hh = lane; hh < 600; hh += 64) s += senti[b * 600 + hh] * outW[c * 600 + hh];
        s = wred_sum(s);
        if (lane == 0) out[b * 3 + c] = s + outb[c];
    }
}

extern "C" void kernel_launch(void* const* d_in, const int* in_sizes, int n_in,
                              void* d_out, int out_size, void* d_ws, size_t ws_size,
                              hipStream_t stream) {
    const int* ctx_ids = (const int*)d_in[0];
    const int* asp_ids = (const int*)d_in[1];
    // d_in[2], d_in[3]: masks (all ones, unused by reference)
    const float* emb   = (const float*)d_in[4];
    const float* Wc    = (const float*)d_in[5];
    const float* Wa    = (const float*)d_in[6];
    const float* Vatt  = (const float*)d_in[7];
    const float* Wlin  = (const float*)d_in[8];
    const float* blin  = (const float*)d_in[9];
    const float* Vw    = (const float*)d_in[10];
    const float* bVw   = (const float*)d_in[11];
    const float* wih_f = (const float*)d_in[12];
    const float* whh_f = (const float*)d_in[13];
    const float* bih_f = (const float*)d_in[14];
    const float* bhh_f = (const float*)d_in[15];
    const float* wih_b = (const float*)d_in[16];
    const float* whh_b = (const float*)d_in[17];
    const float* bih_b = (const float*)d_in[18];
    const float* bhh_b = (const float*)d_in[19];
    const float* outW  = (const float*)d_in[20];
    const float* outb  = (const float*)d_in[21];
    float* ws = (float*)d_ws;

    size_t o = 0;
    float* ctx_emb = ws + o; o += (size_t)B_ * L1_ * D_;
    float* asp_emb = ws + o; o += (size_t)B_ * L2_ * D_;
    float* c_proj  = ws + o; o += (size_t)B_ * L1_ * D_;
    float* a_proj  = ws + o; o += (size_t)B_ * L2_ * D_;
    float* lin_buf = ws + o; o += (size_t)B_ * L1_ * D_;
    float* xg_f    = ws + o; o += (size_t)B_ * L1_ * 3 * H_;
    float* xg_b    = ws + o; o += (size_t)B_ * L1_ * 3 * H_;
    float* blogit  = ws + o; o += (size_t)B_ * L1_;
    float* beta    = ws + o; o += (size_t)B_ * L1_;
    float* senti   = ws + o; o += (size_t)B_ * 2 * H_;
    o = (o + 1) & ~(size_t)1;                 // 8B-align the slot area
    long long* slot = (long long*)(ws + o);   // [2][32][2][304] packets
    const size_t slot_ll = (size_t)2 * 32 * 2 * 304;
    o += slot_ll * 2;

    hipMemsetAsync(slot, 0xFF, slot_ll * sizeof(long long), stream);

    dim3 blk(256);
    const int tot_ctx = B_ * L1_ * 75;
    const int tot_asp = B_ * L2_ * 75;
    gather_kernel<<<dim3((tot_ctx + 255) / 256), blk, 0, stream>>>(emb, ctx_ids, ctx_emb, tot_ctx);
    gather_kernel<<<dim3((tot_asp + 255) / 256), blk, 0, stream>>>(emb, asp_ids, asp_emb, tot_asp);

    gemm_nt<<<dim3(16384 / 128, 5), blk, 0, stream>>>(ctx_emb, Wc, nullptr, c_proj, 16384, 300, 300);
    gemm_nt<<<dim3(16384 / 128, 5), blk, 0, stream>>>(ctx_emb, Wlin, blin, lin_buf, 16384, 300, 300);
    gemm_nt<<<dim3(512 / 128, 5), blk, 0, stream>>>(asp_emb, Wa, nullptr, a_proj, 512, 300, 300);
    gemm_nt<<<dim3(16384 / 128, 15), blk, 0, stream>>>(ctx_emb, wih_f, bih_f, xg_f, 16384, 900, 300);
    gemm_nt<<<dim3(16384 / 128, 15), blk, 0, stream>>>(ctx_emb, wih_b, bih_b, xg_b, 16384, 900, 300);

    attn_kernel<<<dim3(32, 32), blk, 0, stream>>>(c_proj, a_proj, asp_emb, lin_buf, Vatt, Vw, bVw, blogit);
    beta_softmax_kernel<<<dim3(32), blk, 0, stream>>>(blogit, beta);
    gru9_kernel<<<dim3(8, 32), blk, 0, stream>>>(xg_f, xg_b, whh_f, whh_b, bhh_f, bhh_b,
                                                 beta, slot, senti);
    logits_kernel<<<dim3(32), dim3(64), 0, stream>>>(senti, outW, outb, (float*)d_out);
}

// Round 11
// 2471.534 us; speedup vs baseline: 1.7617x; 1.7617x over previous
//
#include <hip/hip_runtime.h>

// Model: B=32, L1=512, L2=16, D=300, H=300, V=50000, C=3
#define B_  32
#define L1_ 512
#define L2_ 16
#define D_  300
#define H_  300

__device__ __forceinline__ float sigmoid_fast(float x) {
    return 1.0f / (1.0f + __expf(-x));
}
__device__ __forceinline__ float tanh_fast(float x) {
    x = fminf(fmaxf(x, -15.0f), 15.0f);
    float e = __expf(2.0f * x);
    return (e - 1.0f) / (e + 1.0f);
}
// accurate versions for the GRU recurrence (R4/R5/R7 evidence: large margin)
__device__ __forceinline__ float sigmoid_acc(float x) {
    return 1.0f / (1.0f + expf(-x));
}
__device__ __forceinline__ float wred_sum(float v) {
    #pragma unroll
    for (int off = 32; off > 0; off >>= 1) v += __shfl_xor(v, off);
    return v;
}
__device__ __forceinline__ float wred_max(float v) {
    #pragma unroll
    for (int off = 32; off > 0; off >>= 1) v = fmaxf(v, __shfl_xor(v, off));
    return v;
}

// device-coherent (LLC) 8-byte packet ops: sc0 sc1 = bypass L1+L2, no invalidates
__device__ __forceinline__ void store_pkt(long long* p, long long v) {
    asm volatile("global_store_dwordx2 %0, %1, off sc0 sc1" :: "v"(p), "v"(v) : "memory");
}
__device__ __forceinline__ long long load_pkt(const long long* p) {
    long long v;
    asm volatile("global_load_dwordx2 %0, %1, off sc0 sc1\n\t"
                 "s_waitcnt vmcnt(0)"
                 : "=v"(v) : "v"(p) : "memory");
    return v;
}

// ---------------- gather rows of emb (row length 300 = 75 float4) ----------------
__global__ __launch_bounds__(256) void gather_kernel(const float* __restrict__ emb,
                                                     const int* __restrict__ ids,
                                                     float* __restrict__ out, int total) {
    for (int i = blockIdx.x * 256 + threadIdx.x; i < total; i += gridDim.x * 256) {
        int row = i / 75, c = i % 75;
        int id = ids[row];
        reinterpret_cast<float4*>(out)[i] =
            reinterpret_cast<const float4*>(emb + (size_t)id * 300)[c];
    }
}

// ---------------- fp32 GEMM v2: C[M,N] = A[M,K] @ W[N,K]^T (+ bias[n]) ----------------
// 128x128 tile, 8x8 microtile (64 FMA : 4 ds_read_b128 per k-step = 16:1).
// LDS columns swizzled phys(c) = c + (c>>5)*4 (row width 140):
//   - max phys index gphys(127) = 139 < 140 (R10 bug: pad*2/width 132 -> OOB)
//   - gphys(8m) % 4 == 0 -> all float4 LDS reads remain 16B-aligned
//   - stage writes 2-way (free), A-reads broadcast, B-reads 2-way (free)
// K tail (300 % 8 = 4) zero-filled.
#define GBM 128
#define GBN 128
#define GBK 8
#define GLW 140
__device__ __forceinline__ int gphys(int c) { return c + ((c >> 5) << 2); }
__global__ __launch_bounds__(256) void gemm128(const float* __restrict__ A,
                                               const float* __restrict__ W,
                                               const float* __restrict__ bias,
                                               float* __restrict__ C,
                                               int M, int N, int K) {
    __shared__ __align__(16) float As[GBK][GLW];
    __shared__ __align__(16) float Bs[GBK][GLW];
    const int tid = threadIdx.x;
    const int m0 = blockIdx.x * GBM;
    const int n0 = blockIdx.y * GBN;
    const int tx = tid & 15;          // output col group
    const int ty = tid >> 4;          // output row group
    const int lrow = tid >> 1;        // staging row 0..127
    const int lq = (tid & 1) * 4;     // staging k quad: 0 or 4
    const int pA = gphys(ty * 8);
    const int pB = gphys(tx * 8);
    const int pS = gphys(lrow);

    float acc[8][8];
    #pragma unroll
    for (int i = 0; i < 8; ++i)
        #pragma unroll
        for (int j = 0; j < 8; ++j) acc[i][j] = 0.f;

    for (int k0 = 0; k0 < K; k0 += GBK) {
        const bool kok = (k0 + lq + 3) < K;
        {   // stage A tile (M rows always in-range: M % 128 == 0)
            float4 v = make_float4(0.f, 0.f, 0.f, 0.f);
            if (kok) v = *reinterpret_cast<const float4*>(&A[(size_t)(m0 + lrow) * K + k0 + lq]);
            As[lq + 0][pS] = v.x;
            As[lq + 1][pS] = v.y;
            As[lq + 2][pS] = v.z;
            As[lq + 3][pS] = v.w;
        }
        {   // stage B tile (guard n < N)
            float4 v = make_float4(0.f, 0.f, 0.f, 0.f);
            const int n = n0 + lrow;
            if (kok && n < N) v = *reinterpret_cast<const float4*>(&W[(size_t)n * K + k0 + lq]);
            Bs[lq + 0][pS] = v.x;
            Bs[lq + 1][pS] = v.y;
            Bs[lq + 2][pS] = v.z;
            Bs[lq + 3][pS] = v.w;
        }
        __syncthreads();
        #pragma unroll
        for (int k = 0; k < GBK; ++k) {
            const float4 a0 = *reinterpret_cast<const float4*>(&As[k][pA]);
            const float4 a1 = *reinterpret_cast<const float4*>(&As[k][pA + 4]);
            const float4 b0 = *reinterpret_cast<const float4*>(&Bs[k][pB]);
            const float4 b1 = *reinterpret_cast<const float4*>(&Bs[k][pB + 4]);
            const float av[8] = {a0.x, a0.y, a0.z, a0.w, a1.x, a1.y, a1.z, a1.w};
            const float bv[8] = {b0.x, b0.y, b0.z, b0.w, b1.x, b1.y, b1.z, b1.w};
            #pragma unroll
            for (int i = 0; i < 8; ++i)
                #pragma unroll
                for (int j = 0; j < 8; ++j) acc[i][j] = fmaf(av[i], bv[j], acc[i][j]);
        }
        __syncthreads();
    }
    // epilogue: float4 stores where in-range (N % 4 == 0 for all our shapes)
    #pragma unroll
    for (int i = 0; i < 8; ++i) {
        const int m = m0 + ty * 8 + i;
        float* crow = C + (size_t)m * N;
        #pragma unroll
        for (int jq = 0; jq < 2; ++jq) {
            const int n = n0 + tx * 8 + jq * 4;
            if (n + 3 < N) {
                float4 v;
                v.x = acc[i][jq * 4 + 0] + (bias ? bias[n + 0] : 0.f);
                v.y = acc[i][jq * 4 + 1] + (bias ? bias[n + 1] : 0.f);
                v.z = acc[i][jq * 4 + 2] + (bias ? bias[n + 2] : 0.f);
                v.w = acc[i][jq * 4 + 3] + (bias ? bias[n + 3] : 0.f);
                *reinterpret_cast<float4*>(&crow[n]) = v;
            } else {
                #pragma unroll
                for (int j = 0; j < 4; ++j) {
                    const int nn = n + j;
                    if (nn < N) crow[nn] = acc[i][jq * 4 + j] + (bias ? bias[nn] : 0.f);
                }
            }
        }
    }
}

// ---------------- attention: scores -> alpha -> context_ -> beta logits ----------------
__global__ __launch_bounds__(256) void attn_kernel(const float* __restrict__ c_proj,
                                                   const float* __restrict__ a_proj,
                                                   const float* __restrict__ asp_emb,
                                                   const float* __restrict__ lin,
                                                   const float* __restrict__ Vatt,
                                                   const float* __restrict__ Vw,
                                                   const float* __restrict__ bVw,
                                                   float* __restrict__ blogit) {
    const int b = blockIdx.y;
    const int chunk = blockIdx.x;
    __shared__ float sA[16 * 300];
    __shared__ float sE[16 * 300];
    __shared__ float sV[300];
    __shared__ float sW[300];
    const int tid = threadIdx.x;
    for (int i = tid; i < 16 * 300; i += 256) {
        sA[i] = a_proj[b * 4800 + i];
        sE[i] = asp_emb[b * 4800 + i];
    }
    for (int i = tid; i < 300; i += 256) {
        sV[i] = Vatt[i];
        sW[i] = Vw[i];
    }
    __syncthreads();
    const int wave = tid >> 6, lane = tid & 63;
    const float bvw = bVw[0];
    for (int li = 0; li < 4; ++li) {
        const int l = chunk * 16 + wave * 4 + li;
        const float* crow = c_proj + (size_t)(b * L1_ + l) * 300;
        float cr[5];
        #pragma unroll
        for (int i = 0; i < 5; ++i) {
            int d = lane + 64 * i;
            cr[i] = (d < 300) ? crow[d] : 0.f;
        }
        float sc[16];
        #pragma unroll
        for (int m = 0; m < 16; ++m) {
            float s = 0.f;
            #pragma unroll
            for (int i = 0; i < 5; ++i) {
                int d = lane + 64 * i;
                if (d < 300) s += tanh_fast(cr[i] + sA[m * 300 + d]) * sV[d];
            }
            s = wred_sum(s);
            sc[m] = s;
        }
        float mx = sc[0];
        #pragma unroll
        for (int m = 1; m < 16; ++m) mx = fmaxf(mx, sc[m]);
        float den = 0.f;
        #pragma unroll
        for (int m = 0; m < 16; ++m) {
            sc[m] = __expf(sc[m] - mx);
            den += sc[m];
        }
        const float inv = 1.f / den;
        const float* lrow = lin + (size_t)(b * L1_ + l) * 300;
        float acc = 0.f;
        #pragma unroll
        for (int i = 0; i < 5; ++i) {
            int d = lane + 64 * i;
            if (d < 300) {
                float cd = 0.f;
                #pragma unroll
                for (int m = 0; m < 16; ++m) cd += sc[m] * sE[m * 300 + d];
                acc += tanh_fast(lrow[d] + cd * inv) * sW[d];
            }
        }
        acc = wred_sum(acc);
        if (lane == 0) blogit[b * L1_ + l] = acc + bvw;
    }
}

// ---------------- beta softmax over L1=512 per batch ----------------
__global__ __launch_bounds__(256) void beta_softmax_kernel(const float* __restrict__ x,
                                                           float* __restrict__ y) {
    const int b = blockIdx.x, tid = threadIdx.x;
    __shared__ float red[4];
    const int wave = tid >> 6, lane = tid & 63;
    float v0 = x[b * 512 + tid];
    float v1 = x[b * 512 + 256 + tid];
    float m = wred_max(fmaxf(v0, v1));
    if (lane == 0) red[wave] = m;
    __syncthreads();
    m = fmaxf(fmaxf(red[0], red[1]), fmaxf(red[2], red[3]));
    float e0 = __expf(v0 - m), e1 = __expf(v1 - m);
    float s = wred_sum(e0 + e1);
    __syncthreads();
    if (lane == 0) red[wave] = s;
    __syncthreads();
    s = red[0] + red[1] + red[2] + red[3];
    const float inv = 1.f / s;
    y[b * 512 + tid] = e0 * inv;
    y[b * 512 + 256 + tid] = e1 * inv;
}

// ---------------- GRU v7 (R7 best: 1.90 ms, absmax 0.0 — UNCHANGED) ----------------
// grid (4,32,2), 256 threads, 1 block/CU. NO barrier, NO atomics: each h
// element is published as an 8B packet {f32 value, i32 step} with a
// device-coherent sc0 sc1 store; readers issue tagged loads and retry until
// tag==step. Tag rides in the same aligned 8B transaction -> no fence,
// placement-independent. Slots double-buffered by step parity; memset 0xFF
// per launch.
__global__ __launch_bounds__(256, 1) void gru7_kernel(const float* __restrict__ xg_f,
                                                      const float* __restrict__ xg_b,
                                                      const float* __restrict__ whh_f,
                                                      const float* __restrict__ whh_b,
                                                      const float* __restrict__ bhh_f,
                                                      const float* __restrict__ bhh_b,
                                                      const float* __restrict__ beta,
                                                      long long* __restrict__ slot, // [2][64][4][80]
                                                      float* __restrict__ senti) {
    const int s = blockIdx.x;    // slice 0..3 (owns h [75s, 75s+75))
    const int b = blockIdx.y;    // 0..31
    const int rev = blockIdx.z;  // 0..1
    const int g = rev * 32 + b;
    const float* xg  = rev ? xg_b : xg_f;
    const float* whh = rev ? whh_b : whh_f;
    const float* bhh = rev ? bhh_b : bhh_f;

    const int tid = threadIdx.x;
    const int e0 = s * 75;
    const bool act = tid < 225;
    const int gate = tid / 75;   // 0=r 1=z 2=n
    const int idx = tid % 75;

    __shared__ __align__(16) float hs[304];
    __shared__ float gg[3][80];

    // ---- weight row -> registers, asm-pinned ----
    float4 w4[75];
    float bh = 0.f;
    if (act) {
        const int row = gate * 300 + e0 + idx;
        bh = bhh[row];
        const float4* wp = reinterpret_cast<const float4*>(whh + (size_t)row * 300);
        #pragma unroll
        for (int j = 0; j < 75; ++j) w4[j] = wp[j];
    } else {
        #pragma unroll
        for (int j = 0; j < 75; ++j) w4[j] = make_float4(0.f, 0.f, 0.f, 0.f);
    }
    #pragma unroll
    for (int j = 0; j < 75; ++j)
        asm volatile("" : "+v"(w4[j].x), "+v"(w4[j].y), "+v"(w4[j].z), "+v"(w4[j].w));
    asm volatile("" : "+v"(bh));

    // reader setup: tid<225 owns one foreign element
    int fsl = 0, fli = 0;
    if (tid < 225) {
        fsl = tid / 75;
        if (fsl >= s) ++fsl;           // skip own slice
        fli = tid % 75;
    }
    long long* wp0 = slot + ((size_t)g * 4 + s) * 80 + tid;            // writer base
    const long long* rbase = slot + ((size_t)g * 4 + fsl) * 80 + fli;  // reader base

    for (int i = tid; i < 304; i += 256) hs[i] = 0.f;
    float sacc = 0.f;
    int gaveup = 0;
    __syncthreads();

    const float4* hs4 = reinterpret_cast<const float4*>(hs);
    for (int step = 0; step < 512; ++step) {
        const int t = rev ? (511 - step) : step;
        // prefetch xg/beta (independent of h; latency hides under the matvec)
        float xr = 0.f, xz = 0.f, xn = 0.f, bt = 0.f;
        if (tid < 75) {
            const float* xrow = xg + (size_t)(b * 512 + t) * 900;
            const int e = e0 + tid;
            xr = xrow[e];
            xz = xrow[300 + e];
            xn = xrow[600 + e];
            bt = beta[b * 512 + t];
        }
        // matvec from pinned registers, 4 accumulators
        float a0 = 0.f, a1 = 0.f, a2 = 0.f, a3 = 0.f;
        #pragma unroll
        for (int j = 0; j < 72; j += 4) {
            float4 hv;
            hv = hs4[j];
            a0 = fmaf(w4[j].x, hv.x, a0); a0 = fmaf(w4[j].y, hv.y, a0);
            a0 = fmaf(w4[j].z, hv.z, a0); a0 = fmaf(w4[j].w, hv.w, a0);
            hv = hs4[j + 1];
            a1 = fmaf(w4[j + 1].x, hv.x, a1); a1 = fmaf(w4[j + 1].y, hv.y, a1);
            a1 = fmaf(w4[j + 1].z, hv.z, a1); a1 = fmaf(w4[j + 1].w, hv.w, a1);
            hv = hs4[j + 2];
            a2 = fmaf(w4[j + 2].x, hv.x, a2); a2 = fmaf(w4[j + 2].y, hv.y, a2);
            a2 = fmaf(w4[j + 2].z, hv.z, a2); a2 = fmaf(w4[j + 2].w, hv.w, a2);
            hv = hs4[j + 3];
            a3 = fmaf(w4[j + 3].x, hv.x, a3); a3 = fmaf(w4[j + 3].y, hv.y, a3);
            a3 = fmaf(w4[j + 3].z, hv.z, a3); a3 = fmaf(w4[j + 3].w, hv.w, a3);
        }
        {   // j = 72, 73, 74 tail
            float4 hv;
            hv = hs4[72];
            a0 = fmaf(w4[72].x, hv.x, a0); a0 = fmaf(w4[72].y, hv.y, a0);
            a0 = fmaf(w4[72].z, hv.z, a0); a0 = fmaf(w4[72].w, hv.w, a0);
            hv = hs4[73];
            a1 = fmaf(w4[73].x, hv.x, a1); a1 = fmaf(w4[73].y, hv.y, a1);
            a1 = fmaf(w4[73].z, hv.z, a1); a1 = fmaf(w4[73].w, hv.w, a1);
            hv = hs4[74];
            a2 = fmaf(w4[74].x, hv.x, a2); a2 = fmaf(w4[74].y, hv.y, a2);
            a2 = fmaf(w4[74].z, hv.z, a2); a2 = fmaf(w4[74].w, hv.w, a2);
        }
        const float acc = bh + ((a0 + a1) + (a2 + a3));
        if (act) gg[gate][idx] = acc;
        __syncthreads();
        // own-slice gate update; publish packet {h, step}
        if (tid < 75) {
            const int e = e0 + tid;
            const float rr = sigmoid_acc(xr + gg[0][tid]);
            const float zz = sigmoid_acc(xz + gg[1][tid]);
            const float nn = tanhf(xn + rr * gg[2][tid]);
            const float hn = (1.f - zz) * nn + zz * hs[e];
            sacc = fmaf(bt, hn, sacc);
            hs[e] = hn;
            if (step < 511) {
                long long pkt = ((long long)(unsigned)step << 32) |
                                (unsigned)__float_as_int(hn);
                store_pkt(wp0 + (size_t)(step & 1) * 64 * 4 * 80, pkt);
            }
        }
        if (step == 511) break;
        // tagged gather of the 3 foreign slices
        if (tid < 225) {
            const long long* p = rbase + (size_t)(step & 1) * 64 * 4 * 80;
            long long v = 0;
            if (!gaveup) {
                int ok = 0;
                for (int it = 0; it < (1 << 16); ++it) {
                    v = load_pkt(p);
                    if (((int)(v >> 32)) == step) { ok = 1; break; }
                }
                if (!ok) gaveup = 1;   // sticky: never hang; keep last value
            } else {
                v = load_pkt(p);
            }
            hs[fsl * 75 + fli] = __int_as_float((int)(v & 0xffffffffLL));
        }
        __syncthreads();
    }
    if (tid < 75) senti[b * 600 + rev * 300 + e0 + tid] = sacc;
}

// ---------------- final logits: (32,600) x (3,600)^T + outb ----------------
__global__ __launch_bounds__(64) void logits_kernel(const float* __restrict__ senti,
                                                    const float* __restrict__ outW,
                                                    const float* __restrict__ outb,
                                                    float* __restrict__ out) {
    const int b = blockIdx.x, lane = threadIdx.x;
    for (int c = 0; c < 3; ++c) {
        float s = 0.f;
        for (int hh = lane; hh < 600; hh += 64) s += senti[b * 600 + hh] * outW[c * 600 + hh];
        s = wred_sum(s);
        if (lane == 0) out[b * 3 + c] = s + outb[c];
    }
}

extern "C" void kernel_launch(void* const* d_in, const int* in_sizes, int n_in,
                              void* d_out, int out_size, void* d_ws, size_t ws_size,
                              hipStream_t stream) {
    const int* ctx_ids = (const int*)d_in[0];
    const int* asp_ids = (const int*)d_in[1];
    // d_in[2], d_in[3]: masks (all ones, unused by reference)
    const float* emb   = (const float*)d_in[4];
    const float* Wc    = (const float*)d_in[5];
    const float* Wa    = (const float*)d_in[6];
    const float* Vatt  = (const float*)d_in[7];
    const float* Wlin  = (const float*)d_in[8];
    const float* blin  = (const float*)d_in[9];
    const float* Vw    = (const float*)d_in[10];
    const float* bVw   = (const float*)d_in[11];
    const float* wih_f = (const float*)d_in[12];
    const float* whh_f = (const float*)d_in[13];
    const float* bih_f = (const float*)d_in[14];
    const float* bhh_f = (const float*)d_in[15];
    const float* wih_b = (const float*)d_in[16];
    const float* whh_b = (const float*)d_in[17];
    const float* bih_b = (const float*)d_in[18];
    const float* bhh_b = (const float*)d_in[19];
    const float* outW  = (const float*)d_in[20];
    const float* outb  = (const float*)d_in[21];
    float* ws = (float*)d_ws;

    size_t o = 0;
    float* ctx_emb = ws + o; o += (size_t)B_ * L1_ * D_;
    float* asp_emb = ws + o; o += (size_t)B_ * L2_ * D_;
    float* c_proj  = ws + o; o += (size_t)B_ * L1_ * D_;
    float* a_proj  = ws + o; o += (size_t)B_ * L2_ * D_;
    float* lin_buf = ws + o; o += (size_t)B_ * L1_ * D_;
    float* xg_f    = ws + o; o += (size_t)B_ * L1_ * 3 * H_;
    float* xg_b    = ws + o; o += (size_t)B_ * L1_ * 3 * H_;
    float* blogit  = ws + o; o += (size_t)B_ * L1_;
    float* beta    = ws + o; o += (size_t)B_ * L1_;
    float* senti   = ws + o; o += (size_t)B_ * 2 * H_;
    o = (o + 1) & ~(size_t)1;                 // 8B-align the slot area
    long long* slot = (long long*)(ws + o);   // [2][64][4][80] packets
    const size_t slot_ll = (size_t)2 * 64 * 4 * 80;
    o += slot_ll * 2;

    hipMemsetAsync(slot, 0xFF, slot_ll * sizeof(long long), stream);

    dim3 blk(256);
    const int tot_ctx = B_ * L1_ * 75;
    const int tot_asp = B_ * L2_ * 75;
    gather_kernel<<<dim3((tot_ctx + 255) / 256), blk, 0, stream>>>(emb, ctx_ids, ctx_emb, tot_ctx);
    gather_kernel<<<dim3((tot_asp + 255) / 256), blk, 0, stream>>>(emb, asp_ids, asp_emb, tot_asp);

    // N=300 -> 3 col tiles; N=900 -> 8 col tiles
    gemm128<<<dim3(16384 / 128, 3), blk, 0, stream>>>(ctx_emb, Wc, nullptr, c_proj, 16384, 300, 300);
    gemm128<<<dim3(16384 / 128, 3), blk, 0, stream>>>(ctx_emb, Wlin, blin, lin_buf, 16384, 300, 300);
    gemm128<<<dim3(512 / 128, 3), blk, 0, stream>>>(asp_emb, Wa, nullptr, a_proj, 512, 300, 300);
    gemm128<<<dim3(16384 / 128, 8), blk, 0, stream>>>(ctx_emb, wih_f, bih_f, xg_f, 16384, 900, 300);
    gemm128<<<dim3(16384 / 128, 8), blk, 0, stream>>>(ctx_emb, wih_b, bih_b, xg_b, 16384, 900, 300);

    attn_kernel<<<dim3(32, 32), blk, 0, stream>>>(c_proj, a_proj, asp_emb, lin_buf, Vatt, Vw, bVw, blogit);
    beta_softmax_kernel<<<dim3(32), blk, 0, stream>>>(blogit, beta);
    gru7_kernel<<<dim3(4, 32, 2), blk, 0, stream>>>(xg_f, xg_b, whh_f, whh_b, bhh_f, bhh_b,
                                                    beta, slot, senti);
    logits_kernel<<<dim3(32), dim3(64), 0, stream>>>(senti, outW, outb, (float*)d_out);
}

// Round 12
// 2431.712 us; speedup vs baseline: 1.7906x; 1.0164x over previous
//
#include <hip/hip_runtime.h>

// Model: B=32, L1=512, L2=16, D=300, H=300, V=50000, C=3
#define B_  32
#define L1_ 512
#define L2_ 16
#define D_  300
#define H_  300

__device__ __forceinline__ float sigmoid_fast(float x) {
    return 1.0f / (1.0f + __expf(-x));
}
__device__ __forceinline__ float tanh_fast(float x) {
    x = fminf(fmaxf(x, -15.0f), 15.0f);
    float e = __expf(2.0f * x);
    return (e - 1.0f) / (e + 1.0f);
}
// accurate versions for the GRU recurrence (R4/R5/R7 evidence: large margin)
__device__ __forceinline__ float sigmoid_acc(float x) {
    return 1.0f / (1.0f + expf(-x));
}
__device__ __forceinline__ float wred_sum(float v) {
    #pragma unroll
    for (int off = 32; off > 0; off >>= 1) v += __shfl_xor(v, off);
    return v;
}
__device__ __forceinline__ float wred_max(float v) {
    #pragma unroll
    for (int off = 32; off > 0; off >>= 1) v = fmaxf(v, __shfl_xor(v, off));
    return v;
}

// device-coherent (LLC) 8-byte packet ops: sc0 sc1 = bypass L1+L2, no invalidates
__device__ __forceinline__ void store_pkt(long long* p, long long v) {
    asm volatile("global_store_dwordx2 %0, %1, off sc0 sc1" :: "v"(p), "v"(v) : "memory");
}
__device__ __forceinline__ long long load_pkt(const long long* p) {
    long long v;
    asm volatile("global_load_dwordx2 %0, %1, off sc0 sc1\n\t"
                 "s_waitcnt vmcnt(0)"
                 : "=v"(v) : "v"(p) : "memory");
    return v;
}

// ---------------- gather rows of emb (row length 300 = 75 float4) ----------------
__global__ __launch_bounds__(256) void gather_kernel(const float* __restrict__ emb,
                                                     const int* __restrict__ ids,
                                                     float* __restrict__ out, int total) {
    for (int i = blockIdx.x * 256 + threadIdx.x; i < total; i += gridDim.x * 256) {
        int row = i / 75, c = i % 75;
        int id = ids[row];
        reinterpret_cast<float4*>(out)[i] =
            reinterpret_cast<const float4*>(emb + (size_t)id * 300)[c];
    }
}

// ---------------- fp32 GEMM v3: C[M,N] = A[M,K] @ W[N,K]^T (+ bias[n]) ----------------
// 128x128 tile, 8x8 microtile, GBK=16 (R11 post-mortem: GBK=8 gave only ~1024
// issue-cycles of FMA per staging barrier — not enough to hide ~900-cycle
// staging latency at the 8x8 microtile's ~3 waves/SIMD occupancy. GBK=16
// doubles compute per barrier round and halves barrier count: 19 vs 38).
// LDS columns swizzled phys(c) = c + (c>>5)*4 (row width 140): max index
// gphys(127)=139 < 140, gphys(8m)%4==0 keeps float4 reads 16B-aligned.
// Stage writes 2-way (free), A-reads broadcast, B-reads 2-way (free).
// K tail (300 % 16 = 12) zero-filled per 4-float quad.
#define GBM 128
#define GBN 128
#define GBK 16
#define GLW 140
__device__ __forceinline__ int gphys(int c) { return c + ((c >> 5) << 2); }
__global__ __launch_bounds__(256) void gemm128(const float* __restrict__ A,
                                               const float* __restrict__ W,
                                               const float* __restrict__ bias,
                                               float* __restrict__ C,
                                               int M, int N, int K) {
    __shared__ __align__(16) float As[GBK][GLW];
    __shared__ __align__(16) float Bs[GBK][GLW];
    const int tid = threadIdx.x;
    const int m0 = blockIdx.x * GBM;
    const int n0 = blockIdx.y * GBN;
    const int tx = tid & 15;          // output col group
    const int ty = tid >> 4;          // output row group
    const int srow = tid >> 2;        // staging row 0..63 (+64 on pass 2)
    const int skq = (tid & 3) * 4;    // staging k quad: 0,4,8,12
    const int pA = gphys(ty * 8);
    const int pB = gphys(tx * 8);

    float acc[8][8];
    #pragma unroll
    for (int i = 0; i < 8; ++i)
        #pragma unroll
        for (int j = 0; j < 8; ++j) acc[i][j] = 0.f;

    for (int k0 = 0; k0 < K; k0 += GBK) {
        const bool kok = (k0 + skq + 3) < K;
        #pragma unroll
        for (int h = 0; h < 2; ++h) {
            const int row = srow + 64 * h;
            const int pS = gphys(row);
            {   // stage A tile (M % 128 == 0: rows always in range)
                float4 v = make_float4(0.f, 0.f, 0.f, 0.f);
                if (kok) v = *reinterpret_cast<const float4*>(&A[(size_t)(m0 + row) * K + k0 + skq]);
                As[skq + 0][pS] = v.x;
                As[skq + 1][pS] = v.y;
                As[skq + 2][pS] = v.z;
                As[skq + 3][pS] = v.w;
            }
            {   // stage B tile (guard n < N)
                float4 v = make_float4(0.f, 0.f, 0.f, 0.f);
                const int n = n0 + row;
                if (kok && n < N) v = *reinterpret_cast<const float4*>(&W[(size_t)n * K + k0 + skq]);
                Bs[skq + 0][pS] = v.x;
                Bs[skq + 1][pS] = v.y;
                Bs[skq + 2][pS] = v.z;
                Bs[skq + 3][pS] = v.w;
            }
        }
        __syncthreads();
        #pragma unroll
        for (int k = 0; k < GBK; ++k) {
            const float4 a0 = *reinterpret_cast<const float4*>(&As[k][pA]);
            const float4 a1 = *reinterpret_cast<const float4*>(&As[k][pA + 4]);
            const float4 b0 = *reinterpret_cast<const float4*>(&Bs[k][pB]);
            const float4 b1 = *reinterpret_cast<const float4*>(&Bs[k][pB + 4]);
            const float av[8] = {a0.x, a0.y, a0.z, a0.w, a1.x, a1.y, a1.z, a1.w};
            const float bv[8] = {b0.x, b0.y, b0.z, b0.w, b1.x, b1.y, b1.z, b1.w};
            #pragma unroll
            for (int i = 0; i < 8; ++i)
                #pragma unroll
                for (int j = 0; j < 8; ++j) acc[i][j] = fmaf(av[i], bv[j], acc[i][j]);
        }
        __syncthreads();
    }
    // epilogue: float4 stores where in-range (N % 4 == 0 for all our shapes)
    #pragma unroll
    for (int i = 0; i < 8; ++i) {
        const int m = m0 + ty * 8 + i;
        float* crow = C + (size_t)m * N;
        #pragma unroll
        for (int jq = 0; jq < 2; ++jq) {
            const int n = n0 + tx * 8 + jq * 4;
            if (n + 3 < N) {
                float4 v;
                v.x = acc[i][jq * 4 + 0] + (bias ? bias[n + 0] : 0.f);
                v.y = acc[i][jq * 4 + 1] + (bias ? bias[n + 1] : 0.f);
                v.z = acc[i][jq * 4 + 2] + (bias ? bias[n + 2] : 0.f);
                v.w = acc[i][jq * 4 + 3] + (bias ? bias[n + 3] : 0.f);
                *reinterpret_cast<float4*>(&crow[n]) = v;
            } else {
                #pragma unroll
                for (int j = 0; j < 4; ++j) {
                    const int nn = n + j;
                    if (nn < N) crow[nn] = acc[i][jq * 4 + j] + (bias ? bias[nn] : 0.f);
                }
            }
        }
    }
}

// ---------------- attention: scores -> alpha -> context_ -> beta logits ----------------
__global__ __launch_bounds__(256) void attn_kernel(const float* __restrict__ c_proj,
                                                   const float* __restrict__ a_proj,
                                                   const float* __restrict__ asp_emb,
                                                   const float* __restrict__ lin,
                                                   const float* __restrict__ Vatt,
                                                   const float* __restrict__ Vw,
                                                   const float* __restrict__ bVw,
                                                   float* __restrict__ blogit) {
    const int b = blockIdx.y;
    const int chunk = blockIdx.x;
    __shared__ float sA[16 * 300];
    __shared__ float sE[16 * 300];
    __shared__ float sV[300];
    __shared__ float sW[300];
    const int tid = threadIdx.x;
    for (int i = tid; i < 16 * 300; i += 256) {
        sA[i] = a_proj[b * 4800 + i];
        sE[i] = asp_emb[b * 4800 + i];
    }
    for (int i = tid; i < 300; i += 256) {
        sV[i] = Vatt[i];
        sW[i] = Vw[i];
    }
    __syncthreads();
    const int wave = tid >> 6, lane = tid & 63;
    const float bvw = bVw[0];
    for (int li = 0; li < 4; ++li) {
        const int l = chunk * 16 + wave * 4 + li;
        const float* crow = c_proj + (size_t)(b * L1_ + l) * 300;
        float cr[5];
        #pragma unroll
        for (int i = 0; i < 5; ++i) {
            int d = lane + 64 * i;
            cr[i] = (d < 300) ? crow[d] : 0.f;
        }
        float sc[16];
        #pragma unroll
        for (int m = 0; m < 16; ++m) {
            float s = 0.f;
            #pragma unroll
            for (int i = 0; i < 5; ++i) {
                int d = lane + 64 * i;
                if (d < 300) s += tanh_fast(cr[i] + sA[m * 300 + d]) * sV[d];
            }
            s = wred_sum(s);
            sc[m] = s;
        }
        float mx = sc[0];
        #pragma unroll
        for (int m = 1; m < 16; ++m) mx = fmaxf(mx, sc[m]);
        float den = 0.f;
        #pragma unroll
        for (int m = 0; m < 16; ++m) {
            sc[m] = __expf(sc[m] - mx);
            den += sc[m];
        }
        const float inv = 1.f / den;
        const float* lrow = lin + (size_t)(b * L1_ + l) * 300;
        float acc = 0.f;
        #pragma unroll
        for (int i = 0; i < 5; ++i) {
            int d = lane + 64 * i;
            if (d < 300) {
                float cd = 0.f;
                #pragma unroll
                for (int m = 0; m < 16; ++m) cd += sc[m] * sE[m * 300 + d];
                acc += tanh_fast(lrow[d] + cd * inv) * sW[d];
            }
        }
        acc = wred_sum(acc);
        if (lane == 0) blogit[b * L1_ + l] = acc + bvw;
    }
}

// ---------------- beta softmax over L1=512 per batch ----------------
__global__ __launch_bounds__(256) void beta_softmax_kernel(const float* __restrict__ x,
                                                           float* __restrict__ y) {
    const int b = blockIdx.x, tid = threadIdx.x;
    __shared__ float red[4];
    const int wave = tid >> 6, lane = tid & 63;
    float v0 = x[b * 512 + tid];
    float v1 = x[b * 512 + 256 + tid];
    float m = wred_max(fmaxf(v0, v1));
    if (lane == 0) red[wave] = m;
    __syncthreads();
    m = fmaxf(fmaxf(red[0], red[1]), fmaxf(red[2], red[3]));
    float e0 = __expf(v0 - m), e1 = __expf(v1 - m);
    float s = wred_sum(e0 + e1);
    __syncthreads();
    if (lane == 0) red[wave] = s;
    __syncthreads();
    s = red[0] + red[1] + red[2] + red[3];
    const float inv = 1.f / s;
    y[b * 512 + tid] = e0 * inv;
    y[b * 512 + 256 + tid] = e1 * inv;
}

// ---------------- GRU v7 (R7 best: 1.90 ms, absmax 0.0 — UNCHANGED) ----------------
// grid (4,32,2), 256 threads, 1 block/CU. NO barrier, NO atomics: each h
// element is published as an 8B packet {f32 value, i32 step} with a
// device-coherent sc0 sc1 store; readers issue tagged loads and retry until
// tag==step. Tag rides in the same aligned 8B transaction -> no fence,
// placement-independent. Slots double-buffered by step parity; memset 0xFF
// per launch.
__global__ __launch_bounds__(256, 1) void gru7_kernel(const float* __restrict__ xg_f,
                                                      const float* __restrict__ xg_b,
                                                      const float* __restrict__ whh_f,
                                                      const float* __restrict__ whh_b,
                                                      const float* __restrict__ bhh_f,
                                                      const float* __restrict__ bhh_b,
                                                      const float* __restrict__ beta,
                                                      long long* __restrict__ slot, // [2][64][4][80]
                                                      float* __restrict__ senti) {
    const int s = blockIdx.x;    // slice 0..3 (owns h [75s, 75s+75))
    const int b = blockIdx.y;    // 0..31
    const int rev = blockIdx.z;  // 0..1
    const int g = rev * 32 + b;
    const float* xg  = rev ? xg_b : xg_f;
    const float* whh = rev ? whh_b : whh_f;
    const float* bhh = rev ? bhh_b : bhh_f;

    const int tid = threadIdx.x;
    const int e0 = s * 75;
    const bool act = tid < 225;
    const int gate = tid / 75;   // 0=r 1=z 2=n
    const int idx = tid % 75;

    __shared__ __align__(16) float hs[304];
    __shared__ float gg[3][80];

    // ---- weight row -> registers, asm-pinned ----
    float4 w4[75];
    float bh = 0.f;
    if (act) {
        const int row = gate * 300 + e0 + idx;
        bh = bhh[row];
        const float4* wp = reinterpret_cast<const float4*>(whh + (size_t)row * 300);
        #pragma unroll
        for (int j = 0; j < 75; ++j) w4[j] = wp[j];
    } else {
        #pragma unroll
        for (int j = 0; j < 75; ++j) w4[j] = make_float4(0.f, 0.f, 0.f, 0.f);
    }
    #pragma unroll
    for (int j = 0; j < 75; ++j)
        asm volatile("" : "+v"(w4[j].x), "+v"(w4[j].y), "+v"(w4[j].z), "+v"(w4[j].w));
    asm volatile("" : "+v"(bh));

    // reader setup: tid<225 owns one foreign element
    int fsl = 0, fli = 0;
    if (tid < 225) {
        fsl = tid / 75;
        if (fsl >= s) ++fsl;           // skip own slice
        fli = tid % 75;
    }
    long long* wp0 = slot + ((size_t)g * 4 + s) * 80 + tid;            // writer base
    const long long* rbase = slot + ((size_t)g * 4 + fsl) * 80 + fli;  // reader base

    for (int i = tid; i < 304; i += 256) hs[i] = 0.f;
    float sacc = 0.f;
    int gaveup = 0;
    __syncthreads();

    const float4* hs4 = reinterpret_cast<const float4*>(hs);
    for (int step = 0; step < 512; ++step) {
        const int t = rev ? (511 - step) : step;
        // prefetch xg/beta (independent of h; latency hides under the matvec)
        float xr = 0.f, xz = 0.f, xn = 0.f, bt = 0.f;
        if (tid < 75) {
            const float* xrow = xg + (size_t)(b * 512 + t) * 900;
            const int e = e0 + tid;
            xr = xrow[e];
            xz = xrow[300 + e];
            xn = xrow[600 + e];
            bt = beta[b * 512 + t];
        }
        // matvec from pinned registers, 4 accumulators
        float a0 = 0.f, a1 = 0.f, a2 = 0.f, a3 = 0.f;
        #pragma unroll
        for (int j = 0; j < 72; j += 4) {
            float4 hv;
            hv = hs4[j];
            a0 = fmaf(w4[j].x, hv.x, a0); a0 = fmaf(w4[j].y, hv.y, a0);
            a0 = fmaf(w4[j].z, hv.z, a0); a0 = fmaf(w4[j].w, hv.w, a0);
            hv = hs4[j + 1];
            a1 = fmaf(w4[j + 1].x, hv.x, a1); a1 = fmaf(w4[j + 1].y, hv.y, a1);
            a1 = fmaf(w4[j + 1].z, hv.z, a1); a1 = fmaf(w4[j + 1].w, hv.w, a1);
            hv = hs4[j + 2];
            a2 = fmaf(w4[j + 2].x, hv.x, a2); a2 = fmaf(w4[j + 2].y, hv.y, a2);
            a2 = fmaf(w4[j + 2].z, hv.z, a2); a2 = fmaf(w4[j + 2].w, hv.w, a2);
            hv = hs4[j + 3];
            a3 = fmaf(w4[j + 3].x, hv.x, a3); a3 = fmaf(w4[j + 3].y, hv.y, a3);
            a3 = fmaf(w4[j + 3].z, hv.z, a3); a3 = fmaf(w4[j + 3].w, hv.w, a3);
        }
        {   // j = 72, 73, 74 tail
            float4 hv;
            hv = hs4[72];
            a0 = fmaf(w4[72].x, hv.x, a0); a0 = fmaf(w4[72].y, hv.y, a0);
            a0 = fmaf(w4[72].z, hv.z, a0); a0 = fmaf(w4[72].w, hv.w, a0);
            hv = hs4[73];
            a1 = fmaf(w4[73].x, hv.x, a1); a1 = fmaf(w4[73].y, hv.y, a1);
            a1 = fmaf(w4[73].z, hv.z, a1); a1 = fmaf(w4[73].w, hv.w, a1);
            hv = hs4[74];
            a2 = fmaf(w4[74].x, hv.x, a2); a2 = fmaf(w4[74].y, hv.y, a2);
            a2 = fmaf(w4[74].z, hv.z, a2); a2 = fmaf(w4[74].w, hv.w, a2);
        }
        const float acc = bh + ((a0 + a1) + (a2 + a3));
        if (act) gg[gate][idx] = acc;
        __syncthreads();
        // own-slice gate update; publish packet {h, step}
        if (tid < 75) {
            const int e = e0 + tid;
            const float rr = sigmoid_acc(xr + gg[0][tid]);
            const float zz = sigmoid_acc(xz + gg[1][tid]);
            const float nn = tanhf(xn + rr * gg[2][tid]);
            const float hn = (1.f - zz) * nn + zz * hs[e];
            sacc = fmaf(bt, hn, sacc);
            hs[e] = hn;
            if (step < 511) {
                long long pkt = ((long long)(unsigned)step << 32) |
                                (unsigned)__float_as_int(hn);
                store_pkt(wp0 + (size_t)(step & 1) * 64 * 4 * 80, pkt);
            }
        }
        if (step == 511) break;
        // tagged gather of the 3 foreign slices
        if (tid < 225) {
            const long long* p = rbase + (size_t)(step & 1) * 64 * 4 * 80;
            long long v = 0;
            if (!gaveup) {
                int ok = 0;
                for (int it = 0; it < (1 << 16); ++it) {
                    v = load_pkt(p);
                    if (((int)(v >> 32)) == step) { ok = 1; break; }
                }
                if (!ok) gaveup = 1;   // sticky: never hang; keep last value
            } else {
                v = load_pkt(p);
            }
            hs[fsl * 75 + fli] = __int_as_float((int)(v & 0xffffffffLL));
        }
        __syncthreads();
    }
    if (tid < 75) senti[b * 600 + rev * 300 + e0 + tid] = sacc;
}

// ---------------- final logits: (32,600) x (3,600)^T + outb ----------------
__global__ __launch_bounds__(64) void logits_kernel(const float* __restrict__ senti,
                                                    const float* __restrict__ outW,
                                                    const float* __restrict__ outb,
                                                    float* __restrict__ out) {
    const int b = blockIdx.x, lane = threadIdx.x;
    for (int c = 0; c < 3; ++c) {
        float s = 0.f;
        for (int hh = lane; hh < 600; hh += 64) s += senti[b * 600 + hh] * outW[c * 600 + hh];
        s = wred_sum(s);
        if (lane == 0) out[b * 3 + c] = s + outb[c];
    }
}

extern "C" void kernel_launch(void* const* d_in, const int* in_sizes, int n_in,
                              void* d_out, int out_size, void* d_ws, size_t ws_size,
                              hipStream_t stream) {
    const int* ctx_ids = (const int*)d_in[0];
    const int* asp_ids = (const int*)d_in[1];
    // d_in[2], d_in[3]: masks (all ones, unused by reference)
    const float* emb   = (const float*)d_in[4];
    const float* Wc    = (const float*)d_in[5];
    const float* Wa    = (const float*)d_in[6];
    const float* Vatt  = (const float*)d_in[7];
    const float* Wlin  = (const float*)d_in[8];
    const float* blin  = (const float*)d_in[9];
    const float* Vw    = (const float*)d_in[10];
    const float* bVw   = (const float*)d_in[11];
    const float* wih_f = (const float*)d_in[12];
    const float* whh_f = (const float*)d_in[13];
    const float* bih_f = (const float*)d_in[14];
    const float* bhh_f = (const float*)d_in[15];
    const float* wih_b = (const float*)d_in[16];
    const float* whh_b = (const float*)d_in[17];
    const float* bih_b = (const float*)d_in[18];
    const float* bhh_b = (const float*)d_in[19];
    const float* outW  = (const float*)d_in[20];
    const float* outb  = (const float*)d_in[21];
    float* ws = (float*)d_ws;

    size_t o = 0;
    float* ctx_emb = ws + o; o += (size_t)B_ * L1_ * D_;
    float* asp_emb = ws + o; o += (size_t)B_ * L2_ * D_;
    float* c_proj  = ws + o; o += (size_t)B_ * L1_ * D_;
    float* a_proj  = ws + o; o += (size_t)B_ * L2_ * D_;
    float* lin_buf = ws + o; o += (size_t)B_ * L1_ * D_;
    float* xg_f    = ws + o; o += (size_t)B_ * L1_ * 3 * H_;
    float* xg_b    = ws + o; o += (size_t)B_ * L1_ * 3 * H_;
    float* blogit  = ws + o; o += (size_t)B_ * L1_;
    float* beta    = ws + o; o += (size_t)B_ * L1_;
    float* senti   = ws + o; o += (size_t)B_ * 2 * H_;
    o = (o + 1) & ~(size_t)1;                 // 8B-align the slot area
    long long* slot = (long long*)(ws + o);   // [2][64][4][80] packets
    const size_t slot_ll = (size_t)2 * 64 * 4 * 80;
    o += slot_ll * 2;

    hipMemsetAsync(slot, 0xFF, slot_ll * sizeof(long long), stream);

    dim3 blk(256);
    const int tot_ctx = B_ * L1_ * 75;
    const int tot_asp = B_ * L2_ * 75;
    gather_kernel<<<dim3((tot_ctx + 255) / 256), blk, 0, stream>>>(emb, ctx_ids, ctx_emb, tot_ctx);
    gather_kernel<<<dim3((tot_asp + 255) / 256), blk, 0, stream>>>(emb, asp_ids, asp_emb, tot_asp);

    // N=300 -> 3 col tiles; N=900 -> 8 col tiles
    gemm128<<<dim3(16384 / 128, 3), blk, 0, stream>>>(ctx_emb, Wc, nullptr, c_proj, 16384, 300, 300);
    gemm128<<<dim3(16384 / 128, 3), blk, 0, stream>>>(ctx_emb, Wlin, blin, lin_buf, 16384, 300, 300);
    gemm128<<<dim3(512 / 128, 3), blk, 0, stream>>>(asp_emb, Wa, nullptr, a_proj, 512, 300, 300);
    gemm128<<<dim3(16384 / 128, 8), blk, 0, stream>>>(ctx_emb, wih_f, bih_f, xg_f, 16384, 900, 300);
    gemm128<<<dim3(16384 / 128, 8), blk, 0, stream>>>(ctx_emb, wih_b, bih_b, xg_b, 16384, 900, 300);

    attn_kernel<<<dim3(32, 32), blk, 0, stream>>>(c_proj, a_proj, asp_emb, lin_buf, Vatt, Vw, bVw, blogit);
    beta_softmax_kernel<<<dim3(32), blk, 0, stream>>>(blogit, beta);
    gru7_kernel<<<dim3(4, 32, 2), blk, 0, stream>>>(xg_f, xg_b, whh_f, whh_b, bhh_f, bhh_b,
                                                    beta, slot, senti);
    logits_kernel<<<dim3(32), dim3(64), 0, stream>>>(senti, outW, outb, (float*)d_out);
}